// Round 17
// baseline (109.973 us; speedup 1.0000x reference)
//
#include <hip/hip_runtime.h>

// B = IN = OUT = 512; T from out_size.
// v_t = P_t @ x^T [OUT,B]; G = x@x^T [B,B]
//   u = k*(M*e^{-t} + a*v);  h = (u>0);  s = (u>0.2)
//   v' = d*v + e*(h@G + bt*colsum(G))
// Round-17: certificate folded into B1. Round-16's cert needed a second
// barrier on every zero-flip step (B2c) -> frozen steps got SLOWER (42.5->
// 44.8). Now the margin test (u(t+k) = uInf + dd^k*(u-uInf); safe iff
// |uInf| > dd*|C| + 1e-4*(...) and signs agree) is computed pre-barrier each
// step; lane0 publishes flag byte + cert byte together; ONE barrier serves
// both. certf==all-waves => barrier-free tail (bit-identical fma sequence).

#define NN 512

// ---- Split-K GEMM: grid 768 = 3 outputs x 4 K-quarters x 64 tiles(64x64).
__global__ __launch_bounds__(256) void gemm_splitk_kernel(
    const float* __restrict__ x, const float* __restrict__ W,
    const float* __restrict__ P0, float* __restrict__ part)
{
    const int tid = threadIdx.x;
    const int bid = blockIdx.x;          // 0..767
    const int out = bid >> 8;            // 0..2
    const int rem = bid & 255;
    const int kq = rem >> 6;             // 0..3
    const int tl = rem & 63;
    const int rb = (tl >> 3) << 6;
    const int cb = (tl & 7) << 6;
    const int kbase = kq << 7;           // 0,128,256,384

    const float* A = ((out == 0) ? W : (out == 1) ? P0 : x) + (size_t)rb * NN;
    const float* Bx = x + (size_t)cb * NN;
    float* D = part + (size_t)(out * 4 + kq) * NN * NN;

    const int tx = tid & 15;
    const int ty = tid >> 4;

    __shared__ float At[32][68];
    __shared__ float Bt[32][68];

    const int lr = tid >> 2;
    const int lk = (tid & 3) << 3;

    float acc[4][4] = {{0.f,0.f,0.f,0.f},{0.f,0.f,0.f,0.f},
                       {0.f,0.f,0.f,0.f},{0.f,0.f,0.f,0.f}};

    float4 a0 = *(const float4*)(A + (size_t)lr * NN + kbase + lk);
    float4 a1 = *(const float4*)(A + (size_t)lr * NN + kbase + lk + 4);
    float4 b0 = *(const float4*)(Bx + (size_t)lr * NN + kbase + lk);
    float4 b1 = *(const float4*)(Bx + (size_t)lr * NN + kbase + lk + 4);

    for (int c = 0; c < 4; ++c) {
        __syncthreads();
        At[lk + 0][lr] = a0.x; At[lk + 1][lr] = a0.y;
        At[lk + 2][lr] = a0.z; At[lk + 3][lr] = a0.w;
        At[lk + 4][lr] = a1.x; At[lk + 5][lr] = a1.y;
        At[lk + 6][lr] = a1.z; At[lk + 7][lr] = a1.w;
        Bt[lk + 0][lr] = b0.x; Bt[lk + 1][lr] = b0.y;
        Bt[lk + 2][lr] = b0.z; Bt[lk + 3][lr] = b0.w;
        Bt[lk + 4][lr] = b1.x; Bt[lk + 5][lr] = b1.y;
        Bt[lk + 6][lr] = b1.z; Bt[lk + 7][lr] = b1.w;
        __syncthreads();

        if (c < 3) {
            const int k0 = kbase + ((c + 1) << 5);
            a0 = *(const float4*)(A + (size_t)lr * NN + k0 + lk);
            a1 = *(const float4*)(A + (size_t)lr * NN + k0 + lk + 4);
            b0 = *(const float4*)(Bx + (size_t)lr * NN + k0 + lk);
            b1 = *(const float4*)(Bx + (size_t)lr * NN + k0 + lk + 4);
        }

#pragma unroll
        for (int k = 0; k < 32; ++k) {
            const float4 av = *(const float4*)&At[k][4 * ty];
            const float4 bv = *(const float4*)&Bt[k][4 * tx];
            const float avs[4] = {av.x, av.y, av.z, av.w};
            const float bvs[4] = {bv.x, bv.y, bv.z, bv.w};
#pragma unroll
            for (int i = 0; i < 4; ++i)
#pragma unroll
                for (int j = 0; j < 4; ++j)
                    acc[i][j] = fmaf(avs[i], bvs[j], acc[i][j]);
        }
    }

#pragma unroll
    for (int i = 0; i < 4; ++i) {
        const int r = rb + 4 * ty + i;
        *(float4*)(D + (size_t)r * NN + cb + 4 * tx) =
            make_float4(acc[i][0], acc[i][1], acc[i][2], acc[i][3]);
    }
}

// ---- combine: finals from partials, pairwise sum; bias+relu for M.
__global__ __launch_bounds__(256) void combine_kernel(
    const float* __restrict__ part, const float* __restrict__ bias,
    float* __restrict__ M, float* __restrict__ V0, float* __restrict__ G)
{
    const int idx = blockIdx.x * 256 + threadIdx.x;   // 0..196607
    const int out = idx >> 16;                        // 0..2
    const int io = idx & 65535;
    const float4* p = (const float4*)(part + (size_t)out * 4 * NN * NN);
    const float4 p0 = p[io];
    const float4 p1 = p[io + 65536];
    const float4 p2 = p[io + 131072];
    const float4 p3 = p[io + 196608];
    float4 s;
    s.x = (p0.x + p1.x) + (p2.x + p3.x);
    s.y = (p0.y + p1.y) + (p2.y + p3.y);
    s.z = (p0.z + p1.z) + (p2.z + p3.z);
    s.w = (p0.w + p1.w) + (p2.w + p3.w);
    if (out == 0) {
        const float bb = bias[io >> 7];
        s.x = fmaxf(s.x + bb, 0.f); s.y = fmaxf(s.y + bb, 0.f);
        s.z = fmaxf(s.z + bb, 0.f); s.w = fmaxf(s.w + bb, 0.f);
        ((float4*)M)[io] = s;
    } else if (out == 1) {
        ((float4*)V0)[io] = s;
    } else {
        ((float4*)G)[io] = s;
    }
}

// ---- acc0 split-K x8: ACC0p[kq] = H0[:,kq-slice] @ G[kq-slice,:],
// H0 = (kk*fmaf(a,V0,M) > 0). grid 512 = 8 kq x 64 tiles(64x64), 4x4 micro.
// Tile-row-0 blocks also emit gs partial colsums for their kq slice.
__global__ __launch_bounds__(256) void acc0_splitk_kernel(
    const float* __restrict__ M, const float* __restrict__ V0,
    const float* __restrict__ G, const float* __restrict__ alpha,
    float* __restrict__ ACC0p, float* __restrict__ gsp)
{
    const int tid = threadIdx.x;
    const int bid = blockIdx.x;          // 0..511
    const int kq = bid >> 6;             // 0..7
    const int tl = bid & 63;
    const int rb = (tl >> 3) << 6;
    const int cb = (tl & 7) << 6;
    const int kbase = kq << 6;           // 64-wide K slice

    const float a = alpha[0];
    const float kk = 0.2f;

    const int tx = tid & 15;
    const int ty = tid >> 4;

    __shared__ float At[32][68];
    __shared__ float Bt[32][68];

    const int ar = tid >> 2;             // 0..63 (A row)
    const int akk = (tid & 3) << 3;      // 0,8,16,24
    const int kb = tid >> 3;             // 0..31 (B k-row)
    const int cl = (tid & 7) << 3;       // 0,8,...,56

    float acc[4][4] = {{0.f,0.f,0.f,0.f},{0.f,0.f,0.f,0.f},
                       {0.f,0.f,0.f,0.f},{0.f,0.f,0.f,0.f}};

    float4 m0 = *(const float4*)(M + (size_t)(rb + ar) * NN + kbase + akk);
    float4 m1 = *(const float4*)(M + (size_t)(rb + ar) * NN + kbase + akk + 4);
    float4 v0 = *(const float4*)(V0 + (size_t)(rb + ar) * NN + kbase + akk);
    float4 v1 = *(const float4*)(V0 + (size_t)(rb + ar) * NN + kbase + akk + 4);
    float4 g0 = *(const float4*)(G + (size_t)(kbase + kb) * NN + cb + cl);
    float4 g1 = *(const float4*)(G + (size_t)(kbase + kb) * NN + cb + cl + 4);

    for (int c = 0; c < 2; ++c) {
        __syncthreads();
        At[akk + 0][ar] = (kk * fmaf(a, v0.x, m0.x) > 0.f) ? 1.f : 0.f;
        At[akk + 1][ar] = (kk * fmaf(a, v0.y, m0.y) > 0.f) ? 1.f : 0.f;
        At[akk + 2][ar] = (kk * fmaf(a, v0.z, m0.z) > 0.f) ? 1.f : 0.f;
        At[akk + 3][ar] = (kk * fmaf(a, v0.w, m0.w) > 0.f) ? 1.f : 0.f;
        At[akk + 4][ar] = (kk * fmaf(a, v1.x, m1.x) > 0.f) ? 1.f : 0.f;
        At[akk + 5][ar] = (kk * fmaf(a, v1.y, m1.y) > 0.f) ? 1.f : 0.f;
        At[akk + 6][ar] = (kk * fmaf(a, v1.z, m1.z) > 0.f) ? 1.f : 0.f;
        At[akk + 7][ar] = (kk * fmaf(a, v1.w, m1.w) > 0.f) ? 1.f : 0.f;
        Bt[kb][cl + 0] = g0.x; Bt[kb][cl + 1] = g0.y;
        Bt[kb][cl + 2] = g0.z; Bt[kb][cl + 3] = g0.w;
        Bt[kb][cl + 4] = g1.x; Bt[kb][cl + 5] = g1.y;
        Bt[kb][cl + 6] = g1.z; Bt[kb][cl + 7] = g1.w;
        __syncthreads();

        if (c < 1) {
            const int k0 = kbase + 32;
            m0 = *(const float4*)(M + (size_t)(rb + ar) * NN + k0 + akk);
            m1 = *(const float4*)(M + (size_t)(rb + ar) * NN + k0 + akk + 4);
            v0 = *(const float4*)(V0 + (size_t)(rb + ar) * NN + k0 + akk);
            v1 = *(const float4*)(V0 + (size_t)(rb + ar) * NN + k0 + akk + 4);
            g0 = *(const float4*)(G + (size_t)(k0 + kb) * NN + cb + cl);
            g1 = *(const float4*)(G + (size_t)(k0 + kb) * NN + cb + cl + 4);
        }

#pragma unroll
        for (int k = 0; k < 32; ++k) {
            const float4 av = *(const float4*)&At[k][4 * ty];
            const float4 bv = *(const float4*)&Bt[k][4 * tx];
            const float avs[4] = {av.x, av.y, av.z, av.w};
            const float bvs[4] = {bv.x, bv.y, bv.z, bv.w};
#pragma unroll
            for (int i = 0; i < 4; ++i)
#pragma unroll
                for (int j = 0; j < 4; ++j)
                    acc[i][j] = fmaf(avs[i], bvs[j], acc[i][j]);
        }
    }

    float* Dp = ACC0p + (size_t)kq * NN * NN;
#pragma unroll
    for (int i = 0; i < 4; ++i) {
        *(float4*)(Dp + (size_t)(rb + 4 * ty + i) * NN + cb + 4 * tx) =
            make_float4(acc[i][0], acc[i][1], acc[i][2], acc[i][3]);
    }

    // fused gs partials: tile-row-0 blocks sum their 64-row kq slice
    if ((tl >> 3) == 0) {
        __syncthreads();
        float* red = &At[0][0];
        const int c = cb + (tid & 63);
        const int g = tid >> 6;           // 0..3
        float s = 0.f;
#pragma unroll 16
        for (int i = 0; i < 16; ++i)
            s += G[(size_t)(kbase + 16 * g + i) * NN + c];
        red[g * 64 + (tid & 63)] = s;
        __syncthreads();
        if (g == 0) {
            const int cc = tid & 63;
            gsp[kq * NN + c] =
                (red[cc] + red[64 + cc]) + (red[128 + cc] + red[192 + cc]);
        }
    }
}

// ---- Main recurrence: 512 blocks x 512 threads. Thread owns col c = tid.
// t=0: acc := sum of 8 ACC0 partials. t>=1: EVERY step computes the tail
// certificate pre-barrier; lane0 publishes {flag, cert} bytes together so the
// SINGLE B1 serves both. certf==all-waves => barrier-free bit-identical tail.
// Transient: list build (B2) + 8-wide named-scalar apply.
__global__ __launch_bounds__(512, 4) void snn_bits10_kernel(
    const float* __restrict__ M, const float* __restrict__ G,
    const float* __restrict__ V0, const float* __restrict__ ACC0p,
    const float* __restrict__ gsp, const float* __restrict__ alpha,
    const float* __restrict__ eta, const float* __restrict__ beta,
    unsigned* __restrict__ sp, int T)
{
    const int tid = threadIdx.x;
    const int w = tid >> 6;
    const int lane = tid & 63;
    const int r = blockIdx.x;

    __shared__ unsigned long long lflag[2];
    __shared__ unsigned long long certf[2];
    __shared__ int wcnt[8];
    __shared__ unsigned short list[528] __attribute__((aligned(16)));

    const float a = alpha[0], e = eta[0], bt = beta[0];
    const float kk = 0.2f;
    const float dd = 0.36787944117144233f;       // exp(-1)
    const float inv1md = 1.5819767068693265f;    // 1/(1-exp(-1))
    const float Vth = 0.2f;

    const size_t rc = (size_t)r * NN + tid;
    const float m = M[rc];
    float v = V0[rc];
    const float gsum =
        ((gsp[tid] + gsp[NN + tid]) + (gsp[2 * NN + tid] + gsp[3 * NN + tid])) +
        ((gsp[4 * NN + tid] + gsp[5 * NN + tid]) + (gsp[6 * NN + tid] + gsp[7 * NN + tid]));
    const float cg = e * bt * gsum;
    const float* Gc = G + tid;

    float acc;
    float em;
    unsigned long long oldw;

    // ---- t = 0: bulk apply from the 8 ACC0 partials
    {
        const float u = kk * fmaf(a, v, m * 1.0f);
        const unsigned long long hb = __ballot(u > 0.f);
        const unsigned long long sb = __ballot(u > Vth);
        if (lane == 0)
            *(unsigned long long*)(sp + (size_t)r * 16 + 2 * w) = sb;
        oldw = hb;
        const float* A0 = ACC0p + rc;
        const size_t S = (size_t)NN * NN;
        acc = ((A0[0] + A0[S]) + (A0[2 * S] + A0[3 * S]))
            + ((A0[4 * S] + A0[5 * S]) + (A0[6 * S] + A0[7 * S]));
        v = fmaf(dd, v, fmaf(e, acc, cg));
        em = dd;
    }

    for (int t = 1; t < T; ++t) {
        const float u = kk * fmaf(a, v, m * em);
        const unsigned long long hb = __ballot(u > 0.f);
        const unsigned long long sb = __ballot(u > Vth);
        const unsigned long long xw = hb ^ oldw;

        // tail certificate, computed pre-barrier every step (cheap ALU):
        // u(t+k) = uInf + dd^k*(u - uInf); safe iff |uInf| dominates.
        const float K0 = fmaf(e, acc, cg);
        const float uInf = kk * (a * (K0 * inv1md));
        const float C = u - uInf;
        const bool okT = ((uInf > 0.f) == (u > 0.f)) &&
            (fabsf(uInf) > fmaf(dd, fabsf(C),
                                1e-4f * (fabsf(uInf) + fabsf(C)) + 1e-12f));
        const unsigned long long okm = __ballot(okT);

        const int p = t & 1;
        if (lane == 0) {
            ((unsigned char*)&lflag[p])[w] = (xw != 0ull) ? (unsigned char)1 : (unsigned char)0;
            ((unsigned char*)&certf[p])[w] =
                (xw == 0ull && okm == 0xFFFFFFFFFFFFFFFFull) ? (unsigned char)1 : (unsigned char)0;
            wcnt[w] = (int)__popcll(xw);
            *(unsigned long long*)(sp + ((size_t)t * NN + r) * 16 + 2 * w) = sb;
        }
        __syncthreads();   // B1 (serves flag AND cert)

        if (certf[p] == 0x0101010101010101ull) {
            // whole block frozen + margin-certified: barrier-free tail.
            v = fmaf(dd, v, K0);
            em *= dd;
            for (int t2 = t + 1; t2 < T; ++t2) {
                const float u2 = kk * fmaf(a, v, m * em);
                const unsigned long long sb2 = __ballot(u2 > Vth);
                if (lane == 0)
                    *(unsigned long long*)(sp + ((size_t)t2 * NN + r) * 16 + 2 * w) = sb2;
                v = fmaf(dd, v, K0);
                em *= dd;
            }
            return;
        }

        if (lflag[p] != 0ull) {
            const int c0 = wcnt[0], c1 = wcnt[1], c2 = wcnt[2], c3 = wcnt[3];
            const int c4 = wcnt[4], c5 = wcnt[5], c6 = wcnt[6], c7 = wcnt[7];
            const int ntot = ((c0 + c1) + (c2 + c3)) + ((c4 + c5) + (c6 + c7));
            int base = 0;
            if (w > 0) base += c0;
            if (w > 1) base += c1;
            if (w > 2) base += c2;
            if (w > 3) base += c3;
            if (w > 4) base += c4;
            if (w > 5) base += c5;
            if (w > 6) base += c6;

            if ((xw >> lane) & 1ull) {
                const int pos = (int)__popcll(xw & ((1ull << lane) - 1ull));
                const unsigned row = (unsigned)((w << 6) + lane);
                const unsigned sgn = (unsigned)((hb >> lane) & 1ull) << 15;
                list[base + pos] = (unsigned short)(row | sgn);
            }
            __syncthreads();   // B2: list ready

            float s0 = 0.f, s1 = 0.f, s2 = 0.f, s3 = 0.f;
            float s4 = 0.f, s5 = 0.f, s6 = 0.f, s7 = 0.f;
            for (int j = 0; j < ntot; j += 8) {
                const uint4 le = *(const uint4*)(list + j);
                const unsigned e0 = le.x & 0xFFFFu, e1 = le.x >> 16;
                const unsigned e2 = le.y & 0xFFFFu, e3 = le.y >> 16;
                const unsigned e4 = le.z & 0xFFFFu, e5 = le.z >> 16;
                const unsigned e6 = le.w & 0xFFFFu, e7 = le.w >> 16;
                const float g0 = Gc[(size_t)(e0 & 511u) << 9];
                const float g1 = Gc[(size_t)(e1 & 511u) << 9];
                const float g2 = Gc[(size_t)(e2 & 511u) << 9];
                const float g3 = Gc[(size_t)(e3 & 511u) << 9];
                const float g4 = Gc[(size_t)(e4 & 511u) << 9];
                const float g5 = Gc[(size_t)(e5 & 511u) << 9];
                const float g6 = Gc[(size_t)(e6 & 511u) << 9];
                const float g7 = Gc[(size_t)(e7 & 511u) << 9];
                s0 += (j + 0 < ntot) ? ((e0 & 0x8000u) ? g0 : -g0) : 0.0f;
                s1 += (j + 1 < ntot) ? ((e1 & 0x8000u) ? g1 : -g1) : 0.0f;
                s2 += (j + 2 < ntot) ? ((e2 & 0x8000u) ? g2 : -g2) : 0.0f;
                s3 += (j + 3 < ntot) ? ((e3 & 0x8000u) ? g3 : -g3) : 0.0f;
                s4 += (j + 4 < ntot) ? ((e4 & 0x8000u) ? g4 : -g4) : 0.0f;
                s5 += (j + 5 < ntot) ? ((e5 & 0x8000u) ? g5 : -g5) : 0.0f;
                s6 += (j + 6 < ntot) ? ((e6 & 0x8000u) ? g6 : -g6) : 0.0f;
                s7 += (j + 7 < ntot) ? ((e7 & 0x8000u) ? g7 : -g7) : 0.0f;
            }
            acc += ((s0 + s1) + (s2 + s3)) + ((s4 + s5) + (s6 + s7));
        }

        oldw = hb;
        v = fmaf(dd, v, fmaf(e, acc, cg));
        em *= dd;
    }
}

// ---- Expand: out[t][b][o] = bit b of sp[t][o]. Coalesced float4 stores.
__global__ __launch_bounds__(256) void expand_kernel(
    const unsigned* __restrict__ sp, float* __restrict__ out)
{
    const int tid = threadIdx.x;
    const int t = blockIdx.x >> 3;
    const int bt8 = blockIdx.x & 7;

    __shared__ uint2 sh[NN];
    const uint2* spw = (const uint2*)sp;
    sh[tid]       = spw[((size_t)t * NN + tid) * 8 + bt8];
    sh[tid + 256] = spw[((size_t)t * NN + tid + 256) * 8 + bt8];
    __syncthreads();

    const int b = bt8 * 64 + (tid >> 2);
    const int sub = tid & 3;
    const int rw = (tid >> 2) >> 5;
    const int bit = b & 31;
    float* op = out + (size_t)t * (NN * NN) + (size_t)b * NN;

#pragma unroll 4
    for (int i = 0; i < 32; ++i) {
        const int o = sub * 4 + i * 16;
        const uint2 w0 = sh[o];
        const uint2 w1 = sh[o + 1];
        const uint2 w2 = sh[o + 2];
        const uint2 w3 = sh[o + 3];
        float4 f;
        f.x = (float)(((rw ? w0.y : w0.x) >> bit) & 1u);
        f.y = (float)(((rw ? w1.y : w1.x) >> bit) & 1u);
        f.z = (float)(((rw ? w2.y : w2.x) >> bit) & 1u);
        f.w = (float)(((rw ? w3.y : w3.x) >> bit) & 1u);
        *(float4*)(op + o) = f;
    }
}

// ================= Fallback path (tiny ws) =================
__global__ __launch_bounds__(256) void gemm64_kernel(
    const float* __restrict__ x, const float* __restrict__ W,
    const float* __restrict__ P0, const float* __restrict__ bias,
    float* __restrict__ M, float* __restrict__ V0, float* __restrict__ G)
{
    const int tid = threadIdx.x;
    const int bid = blockIdx.x;
    const int out = bid >> 6;
    const int tl = bid & 63;
    const int rb = (tl >> 3) << 6;
    const int cb = (tl & 7) << 6;

    const float* A = ((out == 0) ? W : (out == 1) ? P0 : x) + (size_t)rb * NN;
    const float* Bx = x + (size_t)cb * NN;
    float* D = (out == 0) ? M : (out == 1) ? V0 : G;

    const int tx = tid & 15;
    const int ty = tid >> 4;

    __shared__ float At[32][68];
    __shared__ float Bt[32][68];

    const int lr = tid >> 2;
    const int lk = (tid & 3) << 3;

    float acc[4][4] = {{0.f,0.f,0.f,0.f},{0.f,0.f,0.f,0.f},
                       {0.f,0.f,0.f,0.f},{0.f,0.f,0.f,0.f}};

    float4 a0 = *(const float4*)(A + (size_t)lr * NN + lk);
    float4 a1 = *(const float4*)(A + (size_t)lr * NN + lk + 4);
    float4 b0 = *(const float4*)(Bx + (size_t)lr * NN + lk);
    float4 b1 = *(const float4*)(Bx + (size_t)lr * NN + lk + 4);

    for (int c = 0; c < 16; ++c) {
        __syncthreads();
        At[lk + 0][lr] = a0.x; At[lk + 1][lr] = a0.y;
        At[lk + 2][lr] = a0.z; At[lk + 3][lr] = a0.w;
        At[lk + 4][lr] = a1.x; At[lk + 5][lr] = a1.y;
        At[lk + 6][lr] = a1.z; At[lk + 7][lr] = a1.w;
        Bt[lk + 0][lr] = b0.x; Bt[lk + 1][lr] = b0.y;
        Bt[lk + 2][lr] = b0.z; Bt[lk + 3][lr] = b0.w;
        Bt[lk + 4][lr] = b1.x; Bt[lk + 5][lr] = b1.y;
        Bt[lk + 6][lr] = b1.z; Bt[lk + 7][lr] = b1.w;
        __syncthreads();

        if (c < 15) {
            const int k0 = (c + 1) << 5;
            a0 = *(const float4*)(A + (size_t)lr * NN + k0 + lk);
            a1 = *(const float4*)(A + (size_t)lr * NN + k0 + lk + 4);
            b0 = *(const float4*)(Bx + (size_t)lr * NN + k0 + lk);
            b1 = *(const float4*)(Bx + (size_t)lr * NN + k0 + lk + 4);
        }

#pragma unroll
        for (int k = 0; k < 32; ++k) {
            const float4 av = *(const float4*)&At[k][4 * ty];
            const float4 bv = *(const float4*)&Bt[k][4 * tx];
            const float avs[4] = {av.x, av.y, av.z, av.w};
            const float bvs[4] = {bv.x, bv.y, bv.z, bv.w};
#pragma unroll
            for (int i = 0; i < 4; ++i)
#pragma unroll
                for (int j = 0; j < 4; ++j)
                    acc[i][j] = fmaf(avs[i], bvs[j], acc[i][j]);
        }
    }

#pragma unroll
    for (int i = 0; i < 4; ++i) {
        const int r = rb + 4 * ty + i;
        float4 o = make_float4(acc[i][0], acc[i][1], acc[i][2], acc[i][3]);
        if (out == 0) {
            const float bb = bias[r];
            o.x = fmaxf(o.x + bb, 0.f); o.y = fmaxf(o.y + bb, 0.f);
            o.z = fmaxf(o.z + bb, 0.f); o.w = fmaxf(o.w + bb, 0.f);
        }
        *(float4*)(D + (size_t)r * NN + cb + 4 * tx) = o;
    }
}

__global__ __launch_bounds__(256) void colsum_kernel(
    const float* __restrict__ G, float* __restrict__ gs)
{
    __shared__ float red[4][64];
    const int tid = threadIdx.x;
    const int c = (blockIdx.x << 6) + (tid & 63);
    const int g = tid >> 6;
    float s = 0.f;
#pragma unroll 8
    for (int bp = 128 * g; bp < 128 * g + 128; ++bp) s += G[(size_t)bp * NN + c];
    if (g > 0) red[g][tid & 63] = s;
    __syncthreads();
    if (g == 0) gs[c] = ((s + red[1][tid & 63]) + red[2][tid & 63]) + red[3][tid & 63];
}

__global__ __launch_bounds__(256) void snn_step_kernel(
    const float* __restrict__ M, const float* __restrict__ G,
    const float* __restrict__ V0, const float* __restrict__ gs,
    const float* __restrict__ alpha, const float* __restrict__ eta,
    const float* __restrict__ beta, float* __restrict__ out, int T)
{
    const int j = threadIdx.x;
    const int r0 = blockIdx.x * 2;
    const int c0 = 2 * j;
    const float a = alpha[0], e = eta[0], bt = beta[0];
    const float kk = 0.2f, dd = 0.36787944117144233f, Vth = 0.2f;

    float v00 = V0[r0 * NN + c0];
    float v01 = V0[r0 * NN + c0 + 1];
    float v10 = V0[(r0 + 1) * NN + c0];
    float v11 = V0[(r0 + 1) * NN + c0 + 1];
    const float m00 = M[r0 * NN + c0];
    const float m01 = M[r0 * NN + c0 + 1];
    const float m10 = M[(r0 + 1) * NN + c0];
    const float m11 = M[(r0 + 1) * NN + c0 + 1];
    const float gs0 = gs[c0];
    const float gs1 = gs[c0 + 1];

    __shared__ float2 hp[NN];
    float em = 1.0f;
    const float2* Gcol = (const float2*)G + j;

    for (int t = 0; t < T; ++t) {
        const float u00 = kk * (m00 * em + a * v00);
        const float u01 = kk * (m01 * em + a * v01);
        const float u10 = kk * (m10 * em + a * v10);
        const float u11 = kk * (m11 * em + a * v11);

        float* outp = out + (size_t)t * (NN * NN);
        float2 sA = make_float2(u00 > Vth ? 1.f : 0.f, u10 > Vth ? 1.f : 0.f);
        float2 sB = make_float2(u01 > Vth ? 1.f : 0.f, u11 > Vth ? 1.f : 0.f);
        *(float2*)(outp + (size_t)c0 * NN + r0) = sA;
        *(float2*)(outp + (size_t)(c0 + 1) * NN + r0) = sB;

        hp[c0]     = make_float2(u00 > 0.f ? 1.f : 0.f, u10 > 0.f ? 1.f : 0.f);
        hp[c0 + 1] = make_float2(u01 > 0.f ? 1.f : 0.f, u11 > 0.f ? 1.f : 0.f);
        __syncthreads();

        float acc00 = 0.f, acc01 = 0.f, acc10 = 0.f, acc11 = 0.f;
#pragma unroll 8
        for (int bp = 0; bp < NN; ++bp) {
            float2 h = hp[bp];
            float2 g = Gcol[(size_t)bp * 256];
            acc00 = fmaf(h.x, g.x, acc00);
            acc01 = fmaf(h.x, g.y, acc01);
            acc10 = fmaf(h.y, g.x, acc10);
            acc11 = fmaf(h.y, g.y, acc11);
        }

        v00 = dd * v00 + e * (acc00 + bt * gs0);
        v01 = dd * v01 + e * (acc01 + bt * gs1);
        v10 = dd * v10 + e * (acc10 + bt * gs0);
        v11 = dd * v11 + e * (acc11 + bt * gs1);
        em *= dd;
        __syncthreads();
    }
}

extern "C" void kernel_launch(void* const* d_in, const int* in_sizes, int n_in,
                              void* d_out, int out_size, void* d_ws, size_t ws_size,
                              hipStream_t stream)
{
    const float* x     = (const float*)d_in[0];
    const float* W     = (const float*)d_in[1];
    const float* bias  = (const float*)d_in[2];
    const float* alpha = (const float*)d_in[3];
    const float* eta   = (const float*)d_in[4];
    const float* beta  = (const float*)d_in[5];
    const float* P0    = (const float*)d_in[6];
    (void)in_sizes; (void)n_in;

    const int T = out_size / (NN * NN);

    float* ws    = (float*)d_ws;
    float* part  = ws;                         // 12 x [512,512] gemm partials
    float* ACC0p = ws;                         // aliases part (dead after combine)
    float* M     = ws + 12 * NN * NN;          // finals
    float* V0    = ws + 13 * NN * NN;
    float* G     = ws + 14 * NN * NN;
    float* gsp   = ws + 15 * NN * NN;          // [8][512]
    unsigned* sp = (unsigned*)(gsp + 8 * NN);  // [T][512][16] words

    const size_t need_main = ((size_t)15 * NN * NN + 8 * NN) * 4
                             + (size_t)T * NN * 16 * 4;

    if (ws_size >= need_main) {
        hipLaunchKernelGGL(gemm_splitk_kernel, dim3(768), dim3(256), 0, stream,
                           x, W, P0, part);
        hipLaunchKernelGGL(combine_kernel, dim3(768), dim3(256), 0, stream,
                           part, bias, M, V0, G);
        hipLaunchKernelGGL(acc0_splitk_kernel, dim3(512), dim3(256), 0, stream,
                           M, V0, G, alpha, ACC0p, gsp);
        hipLaunchKernelGGL(snn_bits10_kernel, dim3(NN), dim3(512), 0, stream,
                           M, G, V0, ACC0p, gsp, alpha, eta, beta, sp, T);
        hipLaunchKernelGGL(expand_kernel, dim3(T * 8), dim3(256), 0, stream,
                           sp, (float*)d_out);
    } else {
        float* Mf  = ws;
        float* V0f = ws + NN * NN;
        float* Gf  = ws + 2 * NN * NN;
        float* gs2 = ws + 3 * NN * NN;
        hipLaunchKernelGGL(gemm64_kernel, dim3(192), dim3(256), 0, stream,
                           x, W, P0, bias, Mf, V0f, Gf);
        hipLaunchKernelGGL(colsum_kernel, dim3(8), dim3(256), 0, stream, Gf, gs2);
        hipLaunchKernelGGL(snn_step_kernel, dim3(256), dim3(256), 0, stream,
                           Mf, Gf, V0f, gs2, alpha, eta, beta, (float*)d_out, T);
    }
}

// Round 18
// 109.627 us; speedup vs baseline: 1.0032x; 1.0032x over previous
//
#include <hip/hip_runtime.h>

// B = IN = OUT = 512; T from out_size (=64).
// v_t = P_t @ x^T [OUT,B]; G = x@x^T [B,B]
//   u = k*(M*e^{-t} + a*v);  h = (u>0);  s = (u>0.2)
//   v' = d*v + e*(h@G + bt*colsum(G))
// Round-18: the snn barrier loop contained a lane0 GLOBAL store of the spike
// word every step; hipcc emits s_waitcnt vmcnt(0) before s_barrier, so every
// one of the 64 steps paid a serialized L2/HBM store drain (~300-600cy) --
// 64 x 2 blocks/CU x ~800cy ~= the measured 45us. Fix: spike words buffered
// in LDS (sbbuf[64][8], 4KB), bulk-stored cooperatively after the loop. The
// round-17 certificate is removed (provably never fires: any thread with
// uInf~0 blocks it). v/s trajectory identical to rounds 13/15 (absmax 0).

#define NN 512

// ---- Split-K GEMM: grid 768 = 3 outputs x 4 K-quarters x 64 tiles(64x64).
__global__ __launch_bounds__(256) void gemm_splitk_kernel(
    const float* __restrict__ x, const float* __restrict__ W,
    const float* __restrict__ P0, float* __restrict__ part)
{
    const int tid = threadIdx.x;
    const int bid = blockIdx.x;          // 0..767
    const int out = bid >> 8;            // 0..2
    const int rem = bid & 255;
    const int kq = rem >> 6;             // 0..3
    const int tl = rem & 63;
    const int rb = (tl >> 3) << 6;
    const int cb = (tl & 7) << 6;
    const int kbase = kq << 7;           // 0,128,256,384

    const float* A = ((out == 0) ? W : (out == 1) ? P0 : x) + (size_t)rb * NN;
    const float* Bx = x + (size_t)cb * NN;
    float* D = part + (size_t)(out * 4 + kq) * NN * NN;

    const int tx = tid & 15;
    const int ty = tid >> 4;

    __shared__ float At[32][68];
    __shared__ float Bt[32][68];

    const int lr = tid >> 2;
    const int lk = (tid & 3) << 3;

    float acc[4][4] = {{0.f,0.f,0.f,0.f},{0.f,0.f,0.f,0.f},
                       {0.f,0.f,0.f,0.f},{0.f,0.f,0.f,0.f}};

    float4 a0 = *(const float4*)(A + (size_t)lr * NN + kbase + lk);
    float4 a1 = *(const float4*)(A + (size_t)lr * NN + kbase + lk + 4);
    float4 b0 = *(const float4*)(Bx + (size_t)lr * NN + kbase + lk);
    float4 b1 = *(const float4*)(Bx + (size_t)lr * NN + kbase + lk + 4);

    for (int c = 0; c < 4; ++c) {
        __syncthreads();
        At[lk + 0][lr] = a0.x; At[lk + 1][lr] = a0.y;
        At[lk + 2][lr] = a0.z; At[lk + 3][lr] = a0.w;
        At[lk + 4][lr] = a1.x; At[lk + 5][lr] = a1.y;
        At[lk + 6][lr] = a1.z; At[lk + 7][lr] = a1.w;
        Bt[lk + 0][lr] = b0.x; Bt[lk + 1][lr] = b0.y;
        Bt[lk + 2][lr] = b0.z; Bt[lk + 3][lr] = b0.w;
        Bt[lk + 4][lr] = b1.x; Bt[lk + 5][lr] = b1.y;
        Bt[lk + 6][lr] = b1.z; Bt[lk + 7][lr] = b1.w;
        __syncthreads();

        if (c < 3) {
            const int k0 = kbase + ((c + 1) << 5);
            a0 = *(const float4*)(A + (size_t)lr * NN + k0 + lk);
            a1 = *(const float4*)(A + (size_t)lr * NN + k0 + lk + 4);
            b0 = *(const float4*)(Bx + (size_t)lr * NN + k0 + lk);
            b1 = *(const float4*)(Bx + (size_t)lr * NN + k0 + lk + 4);
        }

#pragma unroll
        for (int k = 0; k < 32; ++k) {
            const float4 av = *(const float4*)&At[k][4 * ty];
            const float4 bv = *(const float4*)&Bt[k][4 * tx];
            const float avs[4] = {av.x, av.y, av.z, av.w};
            const float bvs[4] = {bv.x, bv.y, bv.z, bv.w};
#pragma unroll
            for (int i = 0; i < 4; ++i)
#pragma unroll
                for (int j = 0; j < 4; ++j)
                    acc[i][j] = fmaf(avs[i], bvs[j], acc[i][j]);
        }
    }

#pragma unroll
    for (int i = 0; i < 4; ++i) {
        const int r = rb + 4 * ty + i;
        *(float4*)(D + (size_t)r * NN + cb + 4 * tx) =
            make_float4(acc[i][0], acc[i][1], acc[i][2], acc[i][3]);
    }
}

// ---- combine: finals from partials, pairwise sum; bias+relu for M.
__global__ __launch_bounds__(256) void combine_kernel(
    const float* __restrict__ part, const float* __restrict__ bias,
    float* __restrict__ M, float* __restrict__ V0, float* __restrict__ G)
{
    const int idx = blockIdx.x * 256 + threadIdx.x;   // 0..196607
    const int out = idx >> 16;                        // 0..2
    const int io = idx & 65535;
    const float4* p = (const float4*)(part + (size_t)out * 4 * NN * NN);
    const float4 p0 = p[io];
    const float4 p1 = p[io + 65536];
    const float4 p2 = p[io + 131072];
    const float4 p3 = p[io + 196608];
    float4 s;
    s.x = (p0.x + p1.x) + (p2.x + p3.x);
    s.y = (p0.y + p1.y) + (p2.y + p3.y);
    s.z = (p0.z + p1.z) + (p2.z + p3.z);
    s.w = (p0.w + p1.w) + (p2.w + p3.w);
    if (out == 0) {
        const float bb = bias[io >> 7];
        s.x = fmaxf(s.x + bb, 0.f); s.y = fmaxf(s.y + bb, 0.f);
        s.z = fmaxf(s.z + bb, 0.f); s.w = fmaxf(s.w + bb, 0.f);
        ((float4*)M)[io] = s;
    } else if (out == 1) {
        ((float4*)V0)[io] = s;
    } else {
        ((float4*)G)[io] = s;
    }
}

// ---- acc0 split-K x8: ACC0p[kq] = H0[:,kq-slice] @ G[kq-slice,:],
// H0 = (kk*fmaf(a,V0,M) > 0). grid 512 = 8 kq x 64 tiles(64x64), 4x4 micro.
// Tile-row-0 blocks also emit gs partial colsums for their kq slice.
__global__ __launch_bounds__(256) void acc0_splitk_kernel(
    const float* __restrict__ M, const float* __restrict__ V0,
    const float* __restrict__ G, const float* __restrict__ alpha,
    float* __restrict__ ACC0p, float* __restrict__ gsp)
{
    const int tid = threadIdx.x;
    const int bid = blockIdx.x;          // 0..511
    const int kq = bid >> 6;             // 0..7
    const int tl = bid & 63;
    const int rb = (tl >> 3) << 6;
    const int cb = (tl & 7) << 6;
    const int kbase = kq << 6;           // 64-wide K slice

    const float a = alpha[0];
    const float kk = 0.2f;

    const int tx = tid & 15;
    const int ty = tid >> 4;

    __shared__ float At[32][68];
    __shared__ float Bt[32][68];

    const int ar = tid >> 2;             // 0..63 (A row)
    const int akk = (tid & 3) << 3;      // 0,8,16,24
    const int kb = tid >> 3;             // 0..31 (B k-row)
    const int cl = (tid & 7) << 3;       // 0,8,...,56

    float acc[4][4] = {{0.f,0.f,0.f,0.f},{0.f,0.f,0.f,0.f},
                       {0.f,0.f,0.f,0.f},{0.f,0.f,0.f,0.f}};

    float4 m0 = *(const float4*)(M + (size_t)(rb + ar) * NN + kbase + akk);
    float4 m1 = *(const float4*)(M + (size_t)(rb + ar) * NN + kbase + akk + 4);
    float4 v0 = *(const float4*)(V0 + (size_t)(rb + ar) * NN + kbase + akk);
    float4 v1 = *(const float4*)(V0 + (size_t)(rb + ar) * NN + kbase + akk + 4);
    float4 g0 = *(const float4*)(G + (size_t)(kbase + kb) * NN + cb + cl);
    float4 g1 = *(const float4*)(G + (size_t)(kbase + kb) * NN + cb + cl + 4);

    for (int c = 0; c < 2; ++c) {
        __syncthreads();
        At[akk + 0][ar] = (kk * fmaf(a, v0.x, m0.x) > 0.f) ? 1.f : 0.f;
        At[akk + 1][ar] = (kk * fmaf(a, v0.y, m0.y) > 0.f) ? 1.f : 0.f;
        At[akk + 2][ar] = (kk * fmaf(a, v0.z, m0.z) > 0.f) ? 1.f : 0.f;
        At[akk + 3][ar] = (kk * fmaf(a, v0.w, m0.w) > 0.f) ? 1.f : 0.f;
        At[akk + 4][ar] = (kk * fmaf(a, v1.x, m1.x) > 0.f) ? 1.f : 0.f;
        At[akk + 5][ar] = (kk * fmaf(a, v1.y, m1.y) > 0.f) ? 1.f : 0.f;
        At[akk + 6][ar] = (kk * fmaf(a, v1.z, m1.z) > 0.f) ? 1.f : 0.f;
        At[akk + 7][ar] = (kk * fmaf(a, v1.w, m1.w) > 0.f) ? 1.f : 0.f;
        Bt[kb][cl + 0] = g0.x; Bt[kb][cl + 1] = g0.y;
        Bt[kb][cl + 2] = g0.z; Bt[kb][cl + 3] = g0.w;
        Bt[kb][cl + 4] = g1.x; Bt[kb][cl + 5] = g1.y;
        Bt[kb][cl + 6] = g1.z; Bt[kb][cl + 7] = g1.w;
        __syncthreads();

        if (c < 1) {
            const int k0 = kbase + 32;
            m0 = *(const float4*)(M + (size_t)(rb + ar) * NN + k0 + akk);
            m1 = *(const float4*)(M + (size_t)(rb + ar) * NN + k0 + akk + 4);
            v0 = *(const float4*)(V0 + (size_t)(rb + ar) * NN + k0 + akk);
            v1 = *(const float4*)(V0 + (size_t)(rb + ar) * NN + k0 + akk + 4);
            g0 = *(const float4*)(G + (size_t)(k0 + kb) * NN + cb + cl);
            g1 = *(const float4*)(G + (size_t)(k0 + kb) * NN + cb + cl + 4);
        }

#pragma unroll
        for (int k = 0; k < 32; ++k) {
            const float4 av = *(const float4*)&At[k][4 * ty];
            const float4 bv = *(const float4*)&Bt[k][4 * tx];
            const float avs[4] = {av.x, av.y, av.z, av.w};
            const float bvs[4] = {bv.x, bv.y, bv.z, bv.w};
#pragma unroll
            for (int i = 0; i < 4; ++i)
#pragma unroll
                for (int j = 0; j < 4; ++j)
                    acc[i][j] = fmaf(avs[i], bvs[j], acc[i][j]);
        }
    }

    float* Dp = ACC0p + (size_t)kq * NN * NN;
#pragma unroll
    for (int i = 0; i < 4; ++i) {
        *(float4*)(Dp + (size_t)(rb + 4 * ty + i) * NN + cb + 4 * tx) =
            make_float4(acc[i][0], acc[i][1], acc[i][2], acc[i][3]);
    }

    // fused gs partials: tile-row-0 blocks sum their 64-row kq slice
    if ((tl >> 3) == 0) {
        __syncthreads();
        float* red = &At[0][0];
        const int c = cb + (tid & 63);
        const int g = tid >> 6;           // 0..3
        float s = 0.f;
#pragma unroll 16
        for (int i = 0; i < 16; ++i)
            s += G[(size_t)(kbase + 16 * g + i) * NN + c];
        red[g * 64 + (tid & 63)] = s;
        __syncthreads();
        if (g == 0) {
            const int cc = tid & 63;
            gsp[kq * NN + c] =
                (red[cc] + red[64 + cc]) + (red[128 + cc] + red[192 + cc]);
        }
    }
}

// ---- Main recurrence: 512 blocks x 512 threads. Thread owns col c = tid.
// NO global stores inside the barrier loop: spike words buffered in LDS
// (sbbuf[64][8]) and bulk-stored cooperatively after the loop. t=0: acc from
// 8 ACC0 partials. t>=1: frozen = 1 barrier (LDS-only ops before it);
// transient = list build (B2) + 8-wide named-scalar apply.
__global__ __launch_bounds__(512, 4) void snn_bits11_kernel(
    const float* __restrict__ M, const float* __restrict__ G,
    const float* __restrict__ V0, const float* __restrict__ ACC0p,
    const float* __restrict__ gsp, const float* __restrict__ alpha,
    const float* __restrict__ eta, const float* __restrict__ beta,
    unsigned* __restrict__ sp, int T)
{
    const int tid = threadIdx.x;
    const int w = tid >> 6;
    const int lane = tid & 63;
    const int r = blockIdx.x;

    __shared__ unsigned long long sbbuf[64][8];   // [t][wave] spike words
    __shared__ unsigned long long lflag[2];
    __shared__ int wcnt[8];
    __shared__ unsigned short list[528] __attribute__((aligned(16)));

    const float a = alpha[0], e = eta[0], bt = beta[0];
    const float kk = 0.2f;
    const float dd = 0.36787944117144233f;   // exp(-1)
    const float Vth = 0.2f;

    const size_t rc = (size_t)r * NN + tid;
    const float m = M[rc];
    float v = V0[rc];
    const float gsum =
        ((gsp[tid] + gsp[NN + tid]) + (gsp[2 * NN + tid] + gsp[3 * NN + tid])) +
        ((gsp[4 * NN + tid] + gsp[5 * NN + tid]) + (gsp[6 * NN + tid] + gsp[7 * NN + tid]));
    const float cg = e * bt * gsum;
    const float* Gc = G + tid;

    float acc;
    float em;
    unsigned long long oldw;

    // ---- t = 0: bulk apply from the 8 ACC0 partials
    {
        const float u = kk * fmaf(a, v, m * 1.0f);
        const unsigned long long hb = __ballot(u > 0.f);
        const unsigned long long sb = __ballot(u > Vth);
        if (lane == 0) sbbuf[0][w] = sb;          // LDS, not global
        oldw = hb;
        const float* A0 = ACC0p + rc;
        const size_t S = (size_t)NN * NN;
        acc = ((A0[0] + A0[S]) + (A0[2 * S] + A0[3 * S]))
            + ((A0[4 * S] + A0[5 * S]) + (A0[6 * S] + A0[7 * S]));
        v = fmaf(dd, v, fmaf(e, acc, cg));
        em = dd;
    }

    for (int t = 1; t < T; ++t) {
        const float u = kk * fmaf(a, v, m * em);
        const unsigned long long hb = __ballot(u > 0.f);
        const unsigned long long sb = __ballot(u > Vth);
        const unsigned long long xw = hb ^ oldw;
        const int p = t & 1;
        if (lane == 0) {
            ((unsigned char*)&lflag[p])[w] = (xw != 0ull) ? (unsigned char)1 : (unsigned char)0;
            wcnt[w] = (int)__popcll(xw);
            sbbuf[t][w] = sb;                     // LDS, not global
        }
        __syncthreads();   // B1 (only LDS ops pending -> cheap lgkm drain)

        if (lflag[p] != 0ull) {
            const int c0 = wcnt[0], c1 = wcnt[1], c2 = wcnt[2], c3 = wcnt[3];
            const int c4 = wcnt[4], c5 = wcnt[5], c6 = wcnt[6], c7 = wcnt[7];
            const int ntot = ((c0 + c1) + (c2 + c3)) + ((c4 + c5) + (c6 + c7));
            int base = 0;
            if (w > 0) base += c0;
            if (w > 1) base += c1;
            if (w > 2) base += c2;
            if (w > 3) base += c3;
            if (w > 4) base += c4;
            if (w > 5) base += c5;
            if (w > 6) base += c6;

            if ((xw >> lane) & 1ull) {
                const int pos = (int)__popcll(xw & ((1ull << lane) - 1ull));
                const unsigned row = (unsigned)((w << 6) + lane);
                const unsigned sgn = (unsigned)((hb >> lane) & 1ull) << 15;
                list[base + pos] = (unsigned short)(row | sgn);
            }
            __syncthreads();   // B2: list ready

            float s0 = 0.f, s1 = 0.f, s2 = 0.f, s3 = 0.f;
            float s4 = 0.f, s5 = 0.f, s6 = 0.f, s7 = 0.f;
            for (int j = 0; j < ntot; j += 8) {
                const uint4 le = *(const uint4*)(list + j);
                const unsigned e0 = le.x & 0xFFFFu, e1 = le.x >> 16;
                const unsigned e2 = le.y & 0xFFFFu, e3 = le.y >> 16;
                const unsigned e4 = le.z & 0xFFFFu, e5 = le.z >> 16;
                const unsigned e6 = le.w & 0xFFFFu, e7 = le.w >> 16;
                const float g0 = Gc[(size_t)(e0 & 511u) << 9];
                const float g1 = Gc[(size_t)(e1 & 511u) << 9];
                const float g2 = Gc[(size_t)(e2 & 511u) << 9];
                const float g3 = Gc[(size_t)(e3 & 511u) << 9];
                const float g4 = Gc[(size_t)(e4 & 511u) << 9];
                const float g5 = Gc[(size_t)(e5 & 511u) << 9];
                const float g6 = Gc[(size_t)(e6 & 511u) << 9];
                const float g7 = Gc[(size_t)(e7 & 511u) << 9];
                s0 += (j + 0 < ntot) ? ((e0 & 0x8000u) ? g0 : -g0) : 0.0f;
                s1 += (j + 1 < ntot) ? ((e1 & 0x8000u) ? g1 : -g1) : 0.0f;
                s2 += (j + 2 < ntot) ? ((e2 & 0x8000u) ? g2 : -g2) : 0.0f;
                s3 += (j + 3 < ntot) ? ((e3 & 0x8000u) ? g3 : -g3) : 0.0f;
                s4 += (j + 4 < ntot) ? ((e4 & 0x8000u) ? g4 : -g4) : 0.0f;
                s5 += (j + 5 < ntot) ? ((e5 & 0x8000u) ? g5 : -g5) : 0.0f;
                s6 += (j + 6 < ntot) ? ((e6 & 0x8000u) ? g6 : -g6) : 0.0f;
                s7 += (j + 7 < ntot) ? ((e7 & 0x8000u) ? g7 : -g7) : 0.0f;
            }
            acc += ((s0 + s1) + (s2 + s3)) + ((s4 + s5) + (s6 + s7));
        }

        oldw = hb;
        v = fmaf(dd, v, fmaf(e, acc, cg));
        em *= dd;
    }

    // ---- bulk spike store: sp[t][r][word], 16 words (64B) contiguous per t.
    __syncthreads();
    const unsigned* sbw = (const unsigned*)&sbbuf[0][0];   // word k of t = sbw[t*16+k]
    for (int idx = tid; idx < T * 16; idx += 512) {
        const int t = idx >> 4;
        const int word = idx & 15;
        sp[(size_t)t * (NN * 16) + (size_t)r * 16 + word] = sbw[t * 16 + word];
    }
}

// ---- Expand: out[t][b][o] = bit b of sp[t][o]. Coalesced float4 stores.
__global__ __launch_bounds__(256) void expand_kernel(
    const unsigned* __restrict__ sp, float* __restrict__ out)
{
    const int tid = threadIdx.x;
    const int t = blockIdx.x >> 3;
    const int bt8 = blockIdx.x & 7;

    __shared__ uint2 sh[NN];
    const uint2* spw = (const uint2*)sp;
    sh[tid]       = spw[((size_t)t * NN + tid) * 8 + bt8];
    sh[tid + 256] = spw[((size_t)t * NN + tid + 256) * 8 + bt8];
    __syncthreads();

    const int b = bt8 * 64 + (tid >> 2);
    const int sub = tid & 3;
    const int rw = (tid >> 2) >> 5;
    const int bit = b & 31;
    float* op = out + (size_t)t * (NN * NN) + (size_t)b * NN;

#pragma unroll 4
    for (int i = 0; i < 32; ++i) {
        const int o = sub * 4 + i * 16;
        const uint2 w0 = sh[o];
        const uint2 w1 = sh[o + 1];
        const uint2 w2 = sh[o + 2];
        const uint2 w3 = sh[o + 3];
        float4 f;
        f.x = (float)(((rw ? w0.y : w0.x) >> bit) & 1u);
        f.y = (float)(((rw ? w1.y : w1.x) >> bit) & 1u);
        f.z = (float)(((rw ? w2.y : w2.x) >> bit) & 1u);
        f.w = (float)(((rw ? w3.y : w3.x) >> bit) & 1u);
        *(float4*)(op + o) = f;
    }
}

// ================= Fallback path (tiny ws or T>64) =================
__global__ __launch_bounds__(256) void gemm64_kernel(
    const float* __restrict__ x, const float* __restrict__ W,
    const float* __restrict__ P0, const float* __restrict__ bias,
    float* __restrict__ M, float* __restrict__ V0, float* __restrict__ G)
{
    const int tid = threadIdx.x;
    const int bid = blockIdx.x;
    const int out = bid >> 6;
    const int tl = bid & 63;
    const int rb = (tl >> 3) << 6;
    const int cb = (tl & 7) << 6;

    const float* A = ((out == 0) ? W : (out == 1) ? P0 : x) + (size_t)rb * NN;
    const float* Bx = x + (size_t)cb * NN;
    float* D = (out == 0) ? M : (out == 1) ? V0 : G;

    const int tx = tid & 15;
    const int ty = tid >> 4;

    __shared__ float At[32][68];
    __shared__ float Bt[32][68];

    const int lr = tid >> 2;
    const int lk = (tid & 3) << 3;

    float acc[4][4] = {{0.f,0.f,0.f,0.f},{0.f,0.f,0.f,0.f},
                       {0.f,0.f,0.f,0.f},{0.f,0.f,0.f,0.f}};

    float4 a0 = *(const float4*)(A + (size_t)lr * NN + lk);
    float4 a1 = *(const float4*)(A + (size_t)lr * NN + lk + 4);
    float4 b0 = *(const float4*)(Bx + (size_t)lr * NN + lk);
    float4 b1 = *(const float4*)(Bx + (size_t)lr * NN + lk + 4);

    for (int c = 0; c < 16; ++c) {
        __syncthreads();
        At[lk + 0][lr] = a0.x; At[lk + 1][lr] = a0.y;
        At[lk + 2][lr] = a0.z; At[lk + 3][lr] = a0.w;
        At[lk + 4][lr] = a1.x; At[lk + 5][lr] = a1.y;
        At[lk + 6][lr] = a1.z; At[lk + 7][lr] = a1.w;
        Bt[lk + 0][lr] = b0.x; Bt[lk + 1][lr] = b0.y;
        Bt[lk + 2][lr] = b0.z; Bt[lk + 3][lr] = b0.w;
        Bt[lk + 4][lr] = b1.x; Bt[lk + 5][lr] = b1.y;
        Bt[lk + 6][lr] = b1.z; Bt[lk + 7][lr] = b1.w;
        __syncthreads();

        if (c < 15) {
            const int k0 = (c + 1) << 5;
            a0 = *(const float4*)(A + (size_t)lr * NN + k0 + lk);
            a1 = *(const float4*)(A + (size_t)lr * NN + k0 + lk + 4);
            b0 = *(const float4*)(Bx + (size_t)lr * NN + k0 + lk);
            b1 = *(const float4*)(Bx + (size_t)lr * NN + k0 + lk + 4);
        }

#pragma unroll
        for (int k = 0; k < 32; ++k) {
            const float4 av = *(const float4*)&At[k][4 * ty];
            const float4 bv = *(const float4*)&Bt[k][4 * tx];
            const float avs[4] = {av.x, av.y, av.z, av.w};
            const float bvs[4] = {bv.x, bv.y, bv.z, bv.w};
#pragma unroll
            for (int i = 0; i < 4; ++i)
#pragma unroll
                for (int j = 0; j < 4; ++j)
                    acc[i][j] = fmaf(avs[i], bvs[j], acc[i][j]);
        }
    }

#pragma unroll
    for (int i = 0; i < 4; ++i) {
        const int r = rb + 4 * ty + i;
        float4 o = make_float4(acc[i][0], acc[i][1], acc[i][2], acc[i][3]);
        if (out == 0) {
            const float bb = bias[r];
            o.x = fmaxf(o.x + bb, 0.f); o.y = fmaxf(o.y + bb, 0.f);
            o.z = fmaxf(o.z + bb, 0.f); o.w = fmaxf(o.w + bb, 0.f);
        }
        *(float4*)(D + (size_t)r * NN + cb + 4 * tx) = o;
    }
}

__global__ __launch_bounds__(256) void colsum_kernel(
    const float* __restrict__ G, float* __restrict__ gs)
{
    __shared__ float red[4][64];
    const int tid = threadIdx.x;
    const int c = (blockIdx.x << 6) + (tid & 63);
    const int g = tid >> 6;
    float s = 0.f;
#pragma unroll 8
    for (int bp = 128 * g; bp < 128 * g + 128; ++bp) s += G[(size_t)bp * NN + c];
    if (g > 0) red[g][tid & 63] = s;
    __syncthreads();
    if (g == 0) gs[c] = ((s + red[1][tid & 63]) + red[2][tid & 63]) + red[3][tid & 63];
}

__global__ __launch_bounds__(256) void snn_step_kernel(
    const float* __restrict__ M, const float* __restrict__ G,
    const float* __restrict__ V0, const float* __restrict__ gs,
    const float* __restrict__ alpha, const float* __restrict__ eta,
    const float* __restrict__ beta, float* __restrict__ out, int T)
{
    const int j = threadIdx.x;
    const int r0 = blockIdx.x * 2;
    const int c0 = 2 * j;
    const float a = alpha[0], e = eta[0], bt = beta[0];
    const float kk = 0.2f, dd = 0.36787944117144233f, Vth = 0.2f;

    float v00 = V0[r0 * NN + c0];
    float v01 = V0[r0 * NN + c0 + 1];
    float v10 = V0[(r0 + 1) * NN + c0];
    float v11 = V0[(r0 + 1) * NN + c0 + 1];
    const float m00 = M[r0 * NN + c0];
    const float m01 = M[r0 * NN + c0 + 1];
    const float m10 = M[(r0 + 1) * NN + c0];
    const float m11 = M[(r0 + 1) * NN + c0 + 1];
    const float gs0 = gs[c0];
    const float gs1 = gs[c0 + 1];

    __shared__ float2 hp[NN];
    float em = 1.0f;
    const float2* Gcol = (const float2*)G + j;

    for (int t = 0; t < T; ++t) {
        const float u00 = kk * (m00 * em + a * v00);
        const float u01 = kk * (m01 * em + a * v01);
        const float u10 = kk * (m10 * em + a * v10);
        const float u11 = kk * (m11 * em + a * v11);

        float* outp = out + (size_t)t * (NN * NN);
        float2 sA = make_float2(u00 > Vth ? 1.f : 0.f, u10 > Vth ? 1.f : 0.f);
        float2 sB = make_float2(u01 > Vth ? 1.f : 0.f, u11 > Vth ? 1.f : 0.f);
        *(float2*)(outp + (size_t)c0 * NN + r0) = sA;
        *(float2*)(outp + (size_t)(c0 + 1) * NN + r0) = sB;

        hp[c0]     = make_float2(u00 > 0.f ? 1.f : 0.f, u10 > 0.f ? 1.f : 0.f);
        hp[c0 + 1] = make_float2(u01 > 0.f ? 1.f : 0.f, u11 > 0.f ? 1.f : 0.f);
        __syncthreads();

        float acc00 = 0.f, acc01 = 0.f, acc10 = 0.f, acc11 = 0.f;
#pragma unroll 8
        for (int bp = 0; bp < NN; ++bp) {
            float2 h = hp[bp];
            float2 g = Gcol[(size_t)bp * 256];
            acc00 = fmaf(h.x, g.x, acc00);
            acc01 = fmaf(h.x, g.y, acc01);
            acc10 = fmaf(h.y, g.x, acc10);
            acc11 = fmaf(h.y, g.y, acc11);
        }

        v00 = dd * v00 + e * (acc00 + bt * gs0);
        v01 = dd * v01 + e * (acc01 + bt * gs1);
        v10 = dd * v10 + e * (acc10 + bt * gs0);
        v11 = dd * v11 + e * (acc11 + bt * gs1);
        em *= dd;
        __syncthreads();
    }
}

extern "C" void kernel_launch(void* const* d_in, const int* in_sizes, int n_in,
                              void* d_out, int out_size, void* d_ws, size_t ws_size,
                              hipStream_t stream)
{
    const float* x     = (const float*)d_in[0];
    const float* W     = (const float*)d_in[1];
    const float* bias  = (const float*)d_in[2];
    const float* alpha = (const float*)d_in[3];
    const float* eta   = (const float*)d_in[4];
    const float* beta  = (const float*)d_in[5];
    const float* P0    = (const float*)d_in[6];
    (void)in_sizes; (void)n_in;

    const int T = out_size / (NN * NN);

    float* ws    = (float*)d_ws;
    float* part  = ws;                         // 12 x [512,512] gemm partials
    float* ACC0p = ws;                         // aliases part (dead after combine)
    float* M     = ws + 12 * NN * NN;          // finals
    float* V0    = ws + 13 * NN * NN;
    float* G     = ws + 14 * NN * NN;
    float* gsp   = ws + 15 * NN * NN;          // [8][512]
    unsigned* sp = (unsigned*)(gsp + 8 * NN);  // [T][512][16] words

    const size_t need_main = ((size_t)15 * NN * NN + 8 * NN) * 4
                             + (size_t)T * NN * 16 * 4;

    if (ws_size >= need_main && T <= 64) {
        hipLaunchKernelGGL(gemm_splitk_kernel, dim3(768), dim3(256), 0, stream,
                           x, W, P0, part);
        hipLaunchKernelGGL(combine_kernel, dim3(768), dim3(256), 0, stream,
                           part, bias, M, V0, G);
        hipLaunchKernelGGL(acc0_splitk_kernel, dim3(512), dim3(256), 0, stream,
                           M, V0, G, alpha, ACC0p, gsp);
        hipLaunchKernelGGL(snn_bits11_kernel, dim3(NN), dim3(512), 0, stream,
                           M, G, V0, ACC0p, gsp, alpha, eta, beta, sp, T);
        hipLaunchKernelGGL(expand_kernel, dim3(T * 8), dim3(256), 0, stream,
                           sp, (float*)d_out);
    } else {
        float* Mf  = ws;
        float* V0f = ws + NN * NN;
        float* Gf  = ws + 2 * NN * NN;
        float* gs2 = ws + 3 * NN * NN;
        hipLaunchKernelGGL(gemm64_kernel, dim3(192), dim3(256), 0, stream,
                           x, W, P0, bias, Mf, V0f, Gf);
        hipLaunchKernelGGL(colsum_kernel, dim3(8), dim3(256), 0, stream, Gf, gs2);
        hipLaunchKernelGGL(snn_step_kernel, dim3(256), dim3(256), 0, stream,
                           Mf, Gf, V0f, gs2, alpha, eta, beta, (float*)d_out, T);
    }
}